// Round 2
// baseline (164.623 us; speedup 1.0000x reference)
//
#include <hip/hip_runtime.h>
#include <hip/hip_bf16.h>
#include <stdint.h>

typedef __attribute__((ext_vector_type(8))) short bf16x8;
typedef __attribute__((ext_vector_type(4))) float f32x4;
typedef __attribute__((ext_vector_type(4))) unsigned int u32x4;
typedef __attribute__((ext_vector_type(2))) unsigned int u32x2;
typedef unsigned short u16;
typedef unsigned int u32;

#define N_NODES 8192
#define N_EDGES 1024
#define F_DIM   256

__device__ __forceinline__ u16 f2bf(float f) {
    union { float f; u32 u; } v; v.f = f;
    u32 u = v.u;
    u = (u + 0x7FFFu + ((u >> 16) & 1u)) >> 16;   // round-nearest-even
    return (u16)u;
}

// ---------------------------------------------------------------------------
// prep_h: one pass over H [8192 x 1024] fp32.
//   - Hb [8192 x 1024] bf16 (row-major, A-operand of GEMM2)
//   - Ht [1024 x 8192] bf16 (transposed, A-operand of GEMM1)
//   - dv[8192] row sums, de[1024] col sums (exact: sums of 0/1)
// 64x64 tile / block, 256 threads, grid (16, 128).  [unchanged — worked R1]
// ---------------------------------------------------------------------------
__global__ void prep_h(const float* __restrict__ H, u16* __restrict__ Hb,
                       u16* __restrict__ Ht, float* __restrict__ dv,
                       float* __restrict__ de) {
    __shared__ u16 tT[64 * 66];
    __shared__ float dv_s[64];
    __shared__ float de_s[64];
    const int tid = threadIdx.x;
    if (tid < 64) { dv_s[tid] = 0.f; de_s[tid] = 0.f; }
    __syncthreads();
    const int r0 = blockIdx.y * 64;
    const int c0 = blockIdx.x * 64;
    const int lr = tid >> 4;
    const int lc = (tid & 15) * 4;
    float cs0 = 0.f, cs1 = 0.f, cs2 = 0.f, cs3 = 0.f;
#pragma unroll
    for (int i = 0; i < 4; i++) {
        const int row = r0 + lr + i * 16;
        f32x4 v = *(const f32x4*)(&H[(size_t)row * N_EDGES + c0 + lc]);
        atomicAdd(&dv_s[lr + i * 16], v[0] + v[1] + v[2] + v[3]);
        cs0 += v[0]; cs1 += v[1]; cs2 += v[2]; cs3 += v[3];
        const u16 b0 = f2bf(v[0]), b1 = f2bf(v[1]), b2 = f2bf(v[2]), b3 = f2bf(v[3]);
        u32x2 pk; pk[0] = (u32)b0 | ((u32)b1 << 16); pk[1] = (u32)b2 | ((u32)b3 << 16);
        *(u32x2*)(&Hb[(size_t)row * N_EDGES + c0 + lc]) = pk;
        tT[(lc + 0) * 66 + lr + i * 16] = b0;
        tT[(lc + 1) * 66 + lr + i * 16] = b1;
        tT[(lc + 2) * 66 + lr + i * 16] = b2;
        tT[(lc + 3) * 66 + lr + i * 16] = b3;
    }
    atomicAdd(&de_s[lc + 0], cs0);
    atomicAdd(&de_s[lc + 1], cs1);
    atomicAdd(&de_s[lc + 2], cs2);
    atomicAdd(&de_s[lc + 3], cs3);
    __syncthreads();
    if (tid < 64) {
        atomicAdd(&dv[r0 + tid], dv_s[tid]);
        atomicAdd(&de[c0 + tid], de_s[tid]);
    }
#pragma unroll
    for (int i = 0; i < 4; i++) {
        const int er = lr + i * 16;
        const u16 b0 = tT[er * 66 + lc + 0];
        const u16 b1 = tT[er * 66 + lc + 1];
        const u16 b2 = tT[er * 66 + lc + 2];
        const u16 b3 = tT[er * 66 + lc + 3];
        u32x2 pk; pk[0] = (u32)b0 | ((u32)b1 << 16); pk[1] = (u32)b2 | ((u32)b3 << 16);
        *(u32x2*)(&Ht[(size_t)(c0 + er) * N_NODES + r0 + lc]) = pk;
    }
}

// ---------------------------------------------------------------------------
// prep_x: Xst[f][n] = bf16(X[n][f] * rsqrt(dv[n]))  -> [256 x 8192]
// ---------------------------------------------------------------------------
__global__ void prep_x(const float* __restrict__ X, const float* __restrict__ dv,
                       u16* __restrict__ Xst) {
    __shared__ u16 tT[64 * 66];
    const int tid = threadIdx.x;
    const int r0 = blockIdx.y * 64;
    const int c0 = blockIdx.x * 64;
    const int lr = tid >> 4;
    const int lc = (tid & 15) * 4;
#pragma unroll
    for (int i = 0; i < 4; i++) {
        const int row = r0 + lr + i * 16;
        const float s = rsqrtf(dv[row]);
        f32x4 v = *(const f32x4*)(&X[(size_t)row * F_DIM + c0 + lc]);
        tT[(lc + 0) * 66 + lr + i * 16] = f2bf(v[0] * s);
        tT[(lc + 1) * 66 + lr + i * 16] = f2bf(v[1] * s);
        tT[(lc + 2) * 66 + lr + i * 16] = f2bf(v[2] * s);
        tT[(lc + 3) * 66 + lr + i * 16] = f2bf(v[3] * s);
    }
    __syncthreads();
#pragma unroll
    for (int i = 0; i < 4; i++) {
        const int er = lr + i * 16;
        const u16 b0 = tT[er * 66 + lc + 0];
        const u16 b1 = tT[er * 66 + lc + 1];
        const u16 b2 = tT[er * 66 + lc + 2];
        const u16 b3 = tT[er * 66 + lc + 3];
        u32x2 pk; pk[0] = (u32)b0 | ((u32)b1 << 16); pk[1] = (u32)b2 | ((u32)b3 << 16);
        *(u32x2*)(&Xst[(size_t)(c0 + er) * N_NODES + r0 + lc]) = pk;
    }
}

// ---------------------------------------------------------------------------
// gemm128x64: C[M x N] = A[M x K] * Bt[N x K]^T, bf16 in, fp32 accumulate.
// 128x64 tile / block, 256 threads (4 waves, 2m x 2n; wave tile 64x32).
// BK=64 (2 k-steps of 32 per barrier pair). LDS row stride 72 u16 (144 B):
// rows r and r+8 alias -> 2-way bank conflict only (free per m136).
// Fragment layouts (HW-verified m89/m91):
//   A[m=lane&15][k=quad*8+j], Bt[n=lane&15][k=quad*8+j], D col=lane&15,
//   row=quad*4+reg.
// EPI 0: store fp32 partial at outF + blockIdx.z*pstride   (GEMM1 split-K)
// EPI 1: fp32 out = v*rsqrt(rowScale[row]) + bias[col]     (GEMM2 final)
// ---------------------------------------------------------------------------
template <int EPI>
__global__ __launch_bounds__(256)
void gemm128x64(const u16* __restrict__ A, const u16* __restrict__ Bt,
                int K, int lda, int ldb, int kSplit,
                float* __restrict__ outF, int ldc, int pstride,
                const float* __restrict__ rowScale,
                const float* __restrict__ bias) {
    __shared__ u16 As[128 * 72];
    __shared__ u16 Bs[64 * 72];
    const int tid = threadIdx.x;
    const int lane = tid & 63;
    const int wave = tid >> 6;
    const int wm = wave >> 1, wn = wave & 1;
    const int row16 = lane & 15;
    const int quad = lane >> 4;

    const int row0 = blockIdx.y * 128;
    const int col0 = blockIdx.x * 64;
    const int k0 = blockIdx.z * kSplit;
    const int k1 = k0 + kSplit;

    const int sra = tid >> 1;           // 0..127
    const int ska = (tid & 1) * 32;     // u16 units
    const int srb = tid >> 2;           // 0..63
    const int skb = (tid & 3) * 16;

    const u16* gA = A + (size_t)(row0 + sra) * lda + ska;
    const u16* gB = Bt + (size_t)(col0 + srb) * ldb + skb;

    f32x4 acc[4][2] = {};

    for (int k = k0; k < k1; k += 64) {
        u32x4 a0 = *(const u32x4*)(gA + k + 0);
        u32x4 a1 = *(const u32x4*)(gA + k + 8);
        u32x4 a2 = *(const u32x4*)(gA + k + 16);
        u32x4 a3 = *(const u32x4*)(gA + k + 24);
        u32x4 b0 = *(const u32x4*)(gB + k + 0);
        u32x4 b1 = *(const u32x4*)(gB + k + 8);
        *(u32x4*)(&As[sra * 72 + ska + 0])  = a0;
        *(u32x4*)(&As[sra * 72 + ska + 8])  = a1;
        *(u32x4*)(&As[sra * 72 + ska + 16]) = a2;
        *(u32x4*)(&As[sra * 72 + ska + 24]) = a3;
        *(u32x4*)(&Bs[srb * 72 + skb + 0])  = b0;
        *(u32x4*)(&Bs[srb * 72 + skb + 8])  = b1;
        __syncthreads();
#pragma unroll
        for (int ks = 0; ks < 2; ks++) {
            bf16x8 af[4], bfr[2];
#pragma unroll
            for (int i = 0; i < 4; i++)
                af[i] = *(const bf16x8*)(&As[(wm * 64 + i * 16 + row16) * 72 + ks * 32 + quad * 8]);
#pragma unroll
            for (int j = 0; j < 2; j++)
                bfr[j] = *(const bf16x8*)(&Bs[(wn * 32 + j * 16 + row16) * 72 + ks * 32 + quad * 8]);
#pragma unroll
            for (int i = 0; i < 4; i++)
#pragma unroll
                for (int j = 0; j < 2; j++)
                    acc[i][j] = __builtin_amdgcn_mfma_f32_16x16x32_bf16(
                        af[i], bfr[j], acc[i][j], 0, 0, 0);
        }
        __syncthreads();
    }

    float* o = outF + (size_t)blockIdx.z * pstride;
#pragma unroll
    for (int i = 0; i < 4; i++) {
#pragma unroll
        for (int j = 0; j < 2; j++) {
            const int col = col0 + wn * 32 + j * 16 + row16;
#pragma unroll
            for (int r = 0; r < 4; r++) {
                const int row = row0 + wm * 64 + i * 16 + quad * 4 + r;
                float v = acc[i][j][r];
                if (EPI == 0) {
                    o[(size_t)row * ldc + col] = v;
                } else {
                    o[(size_t)row * ldc + col] = v * rsqrtf(rowScale[row]) + bias[col];
                }
            }
        }
    }
}

// ---------------------------------------------------------------------------
// gemm_we: M2t[j][e] = sum_f W[j][f] * (sum_p Metp[p][e][f]) / de[e]  (bf16 out)
// Fuses: split-K reduction of GEMM1 partials + De^-1 scaling + fp32->bf16
// conversion + the tiny (256x1024x256, 134 MF) W-GEMM.
// Tile 64(j) x 64(e), grid (16, 4), 256 threads, 4 waves 2x2, BK=64, K=256.
// ---------------------------------------------------------------------------
__global__ __launch_bounds__(256)
void gemm_we(const float* __restrict__ W, const float* __restrict__ Met,
             const float* __restrict__ de, u16* __restrict__ M2t) {
    __shared__ u16 As[64 * 72];
    __shared__ u16 Bs[64 * 72];
    const int tid = threadIdx.x;
    const int lane = tid & 63;
    const int wave = tid >> 6;
    const int wm = wave >> 1, wn = wave & 1;
    const int row16 = lane & 15;
    const int quad = lane >> 4;

    const int j0 = blockIdx.y * 64;     // M dim (W rows)
    const int e0 = blockIdx.x * 64;     // N dim (edges)

    const int sr = tid >> 2;            // 0..63
    const int fb = (tid & 3) * 16;      // f-offset within BK tile

    const float dei = 1.0f / de[e0 + sr];

    f32x4 acc[2][2] = {};

    for (int k = 0; k < 256; k += 64) {
        // A tile: W[j0+sr][k+fb .. +15] fp32 -> bf16
#pragma unroll
        for (int s = 0; s < 4; s++) {
            f32x4 w = *(const f32x4*)(&W[(size_t)(j0 + sr) * 256 + k + fb + s * 4]);
            u32x2 pk;
            pk[0] = (u32)f2bf(w[0]) | ((u32)f2bf(w[1]) << 16);
            pk[1] = (u32)f2bf(w[2]) | ((u32)f2bf(w[3]) << 16);
            *(u32x2*)(&As[sr * 72 + fb + s * 4]) = pk;
        }
        // B tile: sum 8 split-K partials of Met[e0+sr][k+fb..], scale by 1/de
#pragma unroll
        for (int s = 0; s < 4; s++) {
            f32x4 m = {0.f, 0.f, 0.f, 0.f};
#pragma unroll
            for (int p = 0; p < 8; p++) {
                f32x4 mp = *(const f32x4*)(&Met[(size_t)p * (N_EDGES * F_DIM)
                                               + (size_t)(e0 + sr) * 256 + k + fb + s * 4]);
                m[0] += mp[0]; m[1] += mp[1]; m[2] += mp[2]; m[3] += mp[3];
            }
            u32x2 pk;
            pk[0] = (u32)f2bf(m[0] * dei) | ((u32)f2bf(m[1] * dei) << 16);
            pk[1] = (u32)f2bf(m[2] * dei) | ((u32)f2bf(m[3] * dei) << 16);
            *(u32x2*)(&Bs[sr * 72 + fb + s * 4]) = pk;
        }
        __syncthreads();
#pragma unroll
        for (int ks = 0; ks < 2; ks++) {
            bf16x8 af[2], bfr[2];
#pragma unroll
            for (int i = 0; i < 2; i++)
                af[i] = *(const bf16x8*)(&As[(wm * 32 + i * 16 + row16) * 72 + ks * 32 + quad * 8]);
#pragma unroll
            for (int j = 0; j < 2; j++)
                bfr[j] = *(const bf16x8*)(&Bs[(wn * 32 + j * 16 + row16) * 72 + ks * 32 + quad * 8]);
#pragma unroll
            for (int i = 0; i < 2; i++)
#pragma unroll
                for (int j = 0; j < 2; j++)
                    acc[i][j] = __builtin_amdgcn_mfma_f32_16x16x32_bf16(
                        af[i], bfr[j], acc[i][j], 0, 0, 0);
        }
        __syncthreads();
    }

#pragma unroll
    for (int i = 0; i < 2; i++) {
#pragma unroll
        for (int j = 0; j < 2; j++) {
            const int col = e0 + wn * 32 + j * 16 + row16;
#pragma unroll
            for (int r = 0; r < 4; r++) {
                const int row = j0 + wm * 32 + i * 16 + quad * 4 + r;
                M2t[(size_t)row * N_EDGES + col] = f2bf(acc[i][j][r]);
            }
        }
    }
}

// ---------------------------------------------------------------------------
extern "C" void kernel_launch(void* const* d_in, const int* in_sizes, int n_in,
                              void* d_out, int out_size, void* d_ws, size_t ws_size,
                              hipStream_t stream) {
    (void)in_sizes; (void)n_in; (void)out_size; (void)ws_size;
    const float* X = (const float*)d_in[0];   // [8192 x 256]
    const float* H = (const float*)d_in[1];   // [8192 x 1024]
    const float* W = (const float*)d_in[2];   // [256 x 256]
    const float* b = (const float*)d_in[3];   // [256]
    float* out = (float*)d_out;               // [8192 x 256] fp32

    char* ws = (char*)d_ws;
    float* dv   = (float*)(ws);                // 32 KB
    float* de   = (float*)(ws + 0x8000);       // 4 KB
    float* Macc = (float*)(ws + 0x10000);      // 8 MB: 8 x [1024 x 256] fp32 partials
    u16*   Hb   = (u16*)(ws + 0x810000);       // 16 MB [8192 x 1024]
    u16*   Ht   = (u16*)(ws + 0x1810000);      // 16 MB [1024 x 8192]
    u16*   Xst  = (u16*)(ws + 0x2810000);      // 4 MB  [256 x 8192]
    u16*   M2t  = (u16*)(ws + 0x2C10000);      // 512 KB [256 x 1024]

    // zero dv + de only (GEMM1 partials are plain stores, no init needed)
    hipMemsetAsync(ws, 0, 0x9000, stream);

    prep_h<<<dim3(16, 128), 256, 0, stream>>>(H, Hb, Ht, dv, de);
    prep_x<<<dim3(4, 128), 256, 0, stream>>>(X, dv, Xst);

    // GEMM1: Met_p[e][f] partials; M=1024(e), N=256(f), K=8192(n), split-K=8.
    // A=Ht [1024 x 8192], Bt=Xst [256 x 8192]. grid (4,8,8)=256 blocks.
    gemm128x64<0><<<dim3(4, 8, 8), 256, 0, stream>>>(
        Ht, Xst, 8192, 8192, 8192, 1024, Macc, 256, N_EDGES * F_DIM, nullptr, nullptr);

    // fused: reduce partials + De^-1 + W-GEMM -> M2t[j][e] bf16 [256 x 1024]
    gemm_we<<<dim3(16, 4), 256, 0, stream>>>(W, Macc, de, M2t);

    // GEMM2: out[n][j] = rsqrt(dv[n]) * sum_e Hb[n][e]*M2t[j][e] + b[j]
    // M=8192(n), N=256(j), K=1024(e). grid (4,64)=256 blocks.
    gemm128x64<1><<<dim3(4, 64, 1), 256, 0, stream>>>(
        Hb, M2t, 1024, 1024, 1024, 1024, out, 256, 0, dv, b);
}